// Round 1
// baseline (438.792 us; speedup 1.0000x reference)
//
#include <hip/hip_runtime.h>

// Haar wavelet transform, 14 levels, rows of 16384 f32, batch 64*64 = 4096 rows.
// Output = cA_1 (8192/row) ++ cA_2 (4096/row) ++ ... ++ cA_14 (1/row) ++ cD_14 (1/row).
// Reference: cA = (even - odd) * 1/sqrt2, cD = (even + odd) * 1/sqrt2, recurse on cD.

constexpr int ROW_LEN = 16384;   // 2^14
constexpr int LEVELS  = 14;
constexpr int NROWS   = 64 * 64; // 4096
constexpr int NT      = 256;     // threads per block (one block per row)

__global__ __launch_bounds__(NT) void haar_kernel(const float* __restrict__ in,
                                                  float* __restrict__ out) {
    // LDS holds only the level-1 detail coefficients: 8192 floats = 32 KB
    // -> 5 blocks/CU (160 KB LDS), 20 waves/CU.
    __shared__ float lds[ROW_LEN / 2];

    const int row = blockIdx.x;
    const int tid = threadIdx.x;
    const float k = 0.70710678118654752440f; // 1/sqrt(2)

    const float4* rin = (const float4*)(in + (size_t)row * ROW_LEN);
    float2* out1 = (float2*)(out + (size_t)row * (ROW_LEN / 2));
    float2* ldsv = (float2*)lds;

    // ---- Level 1: registers only. Each thread handles 4 contiguous elements
    // per iteration: float4 load (coalesced), float2 cA store (coalesced),
    // float2 cD write to LDS (2-way bank alias across 64 lanes -> free).
    #pragma unroll
    for (int it = 0; it < ROW_LEN / (4 * NT); ++it) {   // 16 iterations
        int tp = it * NT + tid;                          // [0, 4096)
        float4 v = rin[tp];
        float2 ca, cd;
        ca.x = (v.x - v.y) * k;
        ca.y = (v.z - v.w) * k;
        cd.x = (v.x + v.y) * k;
        cd.y = (v.z + v.w) * k;
        out1[tp] = ca;      // cA_1, contiguous per lane
        ldsv[tp] = cd;      // cD_1 dense in LDS
    }
    __syncthreads();

    // ---- Levels 2..14: in-place strided scheme in LDS.
    // Invariant entering level L: cD_{L-1}[i] lives at lds[i << (L-2)]
    // (dense for L=2). Each thread reads lds[base], lds[base+stride] and
    // writes cD_L back to lds[base]; base is only ever touched by its own
    // thread within a level, so one barrier per level suffices.
    size_t chunk_off = (size_t)NROWS * (ROW_LEN / 2);   // past cA_1 chunk
    for (int L = 2; L <= LEVELS; ++L) {
        const int n_out  = ROW_LEN >> L;        // 4096 ... 1
        const int stride = 1 << (L - 2);        // gap between even/odd slots
        float* outL = out + chunk_off + (size_t)row * n_out;
        for (int i = tid; i < n_out; i += NT) {
            const int base = i << (L - 1);
            const float even = lds[base];
            const float odd  = lds[base + stride];
            outL[i]   = (even - odd) * k;       // cA_L, coalesced
            lds[base] = (even + odd) * k;       // cD_L
        }
        chunk_off += (size_t)NROWS * n_out;
        __syncthreads();
    }

    // ---- Final approximation chunk: cD_14 (one element per row).
    if (tid == 0) {
        out[chunk_off + row] = lds[0];
    }
}

extern "C" void kernel_launch(void* const* d_in, const int* in_sizes, int n_in,
                              void* d_out, int out_size, void* d_ws, size_t ws_size,
                              hipStream_t stream) {
    const float* x = (const float*)d_in[0];
    float* out = (float*)d_out;
    haar_kernel<<<dim3(NROWS), dim3(NT), 0, stream>>>(x, out);
}

// Round 2
// 433.659 us; speedup vs baseline: 1.0118x; 1.0118x over previous
//
#include <hip/hip_runtime.h>

// Haar wavelet transform, 14 levels, rows of 16384 f32, batch 64*64 = 4096 rows.
// Output = cA_1 (8192/row) ++ cA_2 ++ ... ++ cA_14 (1/row) ++ cD_14 (1/row).
// cA = (even - odd)/sqrt2, cD = (even + odd)/sqrt2, recurse on cD.
//
// R2 structure: levels 1-3 computed entirely in registers (each thread owns 8
// contiguous inputs -> all operand pairs for cA1x4, cA2x2, cA3x1, cD3x1).
// Only cD3 (2048 floats = 8 KB) goes to LDS -> occupancy is wave-capped at
// 8 blocks/CU (32 waves/CU) instead of LDS-capped at 5. Levels 4-14 in-place
// strided in LDS with one barrier per level.

constexpr int ROW_LEN = 16384;   // 2^14
constexpr int LEVELS  = 14;
constexpr int NROWS   = 64 * 64; // 4096
constexpr int NT      = 256;     // threads per block (one block per row)

__global__ __launch_bounds__(NT) void haar_kernel(const float* __restrict__ in,
                                                  float* __restrict__ out) {
    __shared__ float lds[ROW_LEN / 8];   // cD_3 only: 2048 floats = 8 KB

    const int row = blockIdx.x;
    const int tid = threadIdx.x;
    const float k = 0.70710678118654752440f; // 1/sqrt(2)

    const float4* rin4 = (const float4*)(in + (size_t)row * ROW_LEN);
    float4* out1 = (float4*)(out + (size_t)row * (ROW_LEN / 2));
    float2* out2 = (float2*)(out + (size_t)NROWS * (ROW_LEN / 2)
                                 + (size_t)row * (ROW_LEN / 4));
    float*  out3 = out + (size_t)NROWS * (ROW_LEN / 2 + ROW_LEN / 4)
                       + (size_t)row * (ROW_LEN / 8);

    // ---- Levels 1-3 in registers: 8 contiguous elements per thread per iter.
    #pragma unroll
    for (int it = 0; it < ROW_LEN / (8 * NT); ++it) {   // 8 iterations
        int tp = it * NT + tid;                          // [0, 2048)
        float4 v0 = rin4[2 * tp];
        float4 v1 = rin4[2 * tp + 1];

        // level 1
        float4 ca1;
        ca1.x = (v0.x - v0.y) * k;
        ca1.y = (v0.z - v0.w) * k;
        ca1.z = (v1.x - v1.y) * k;
        ca1.w = (v1.z - v1.w) * k;
        float d0 = (v0.x + v0.y) * k;
        float d1 = (v0.z + v0.w) * k;
        float d2 = (v1.x + v1.y) * k;
        float d3 = (v1.z + v1.w) * k;

        // level 2
        float2 ca2;
        ca2.x = (d0 - d1) * k;
        ca2.y = (d2 - d3) * k;
        float e0 = (d0 + d1) * k;
        float e1 = (d2 + d3) * k;

        // level 3
        float ca3 = (e0 - e1) * k;
        float cd3 = (e0 + e1) * k;

        out1[tp] = ca1;      // coalesced float4
        out2[tp] = ca2;      // coalesced float2
        out3[tp] = ca3;      // coalesced float
        lds[tp]  = cd3;      // dense, 2 lanes/bank = conflict-free
    }
    __syncthreads();

    // ---- Levels 4..14: in-place strided scheme in LDS.
    // Invariant entering level L: cD_{L-1}[i] lives at lds[i << (L-4)].
    // Each thread reads lds[base], lds[base+stride], writes cD_L to lds[base];
    // base is private to its thread within a level -> one barrier per level.
    size_t chunk_off = (size_t)NROWS * (ROW_LEN / 2 + ROW_LEN / 4 + ROW_LEN / 8);
    for (int L = 4; L <= LEVELS; ++L) {
        const int n_out  = ROW_LEN >> L;        // 1024 ... 1
        const int stride = 1 << (L - 4);
        float* outL = out + chunk_off + (size_t)row * n_out;
        for (int i = tid; i < n_out; i += NT) {
            const int base = i << (L - 3);
            const float even = lds[base];
            const float odd  = lds[base + stride];
            outL[i]   = (even - odd) * k;       // cA_L, coalesced
            lds[base] = (even + odd) * k;       // cD_L
        }
        chunk_off += (size_t)NROWS * n_out;
        __syncthreads();
    }

    // ---- Final approximation chunk: cD_14 (one element per row).
    if (tid == 0) {
        out[chunk_off + row] = lds[0];
    }
}

extern "C" void kernel_launch(void* const* d_in, const int* in_sizes, int n_in,
                              void* d_out, int out_size, void* d_ws, size_t ws_size,
                              hipStream_t stream) {
    const float* x = (const float*)d_in[0];
    float* out = (float*)d_out;
    haar_kernel<<<dim3(NROWS), dim3(NT), 0, stream>>>(x, out);
}